// Round 1
// 753.930 us; speedup vs baseline: 1.0840x; 1.0840x over previous
//
#include <hip/hip_runtime.h>
#include <math.h>

#define N_NODES 100000
#define N_EDGES 1600000
#define RREL 4
#define DDIM 128
#define KDIM 512      // RREL*DDIM
#define NKEY 400000   // N_NODES*RREL

typedef __bf16 bf16x8 __attribute__((ext_vector_type(8)));
typedef float f32x4 __attribute__((ext_vector_type(4)));

__device__ __forceinline__ float bflo(unsigned u){ return __builtin_bit_cast(float, u << 16); }
__device__ __forceinline__ float bfhi(unsigned u){ return __builtin_bit_cast(float, u & 0xffff0000u); }
__device__ __forceinline__ unsigned f2bf(float f){
  unsigned u = __builtin_bit_cast(unsigned, f);
  return (u + 0x7fffu + ((u >> 16) & 1u)) >> 16;   // RNE, finite inputs
}
__device__ __forceinline__ int iclamp(int v, int lo, int hi){
  return v < lo ? lo : (v > hi ? hi : v);
}

// ---------------- counting sort of edges by key = dst*4 + et ----------------

__global__ void hist_kernel(const int* __restrict__ dst, const int* __restrict__ et,
                            int* __restrict__ counts){
  int e = blockIdx.x * 256 + threadIdx.x;
  int key = iclamp(dst[e] * RREL + et[e], 0, NKEY - 1);
  atomicAdd(&counts[key], 1);
}

__global__ void scan_local(const int* __restrict__ in, int* __restrict__ out,
                           int* __restrict__ bsums, int K){
  __shared__ int s[1024];
  int t = threadIdx.x;
  int i = blockIdx.x * 1024 + t;
  int v = (i < K) ? in[i] : 0;
  s[t] = v; __syncthreads();
  for (int off = 1; off < 1024; off <<= 1){
    int x = (t >= off) ? s[t - off] : 0;
    __syncthreads();
    s[t] += x;
    __syncthreads();
  }
  if (i < K) out[i] = s[t] - v;           // exclusive within block
  if (t == 1023) bsums[blockIdx.x] = s[t];
}

__global__ void scan_sums(int* __restrict__ b, int nb){
  __shared__ int s[1024];
  int t = threadIdx.x;
  int v = (t < nb) ? b[t] : 0;
  s[t] = v; __syncthreads();
  for (int off = 1; off < 1024; off <<= 1){
    int x = (t >= off) ? s[t - off] : 0;
    __syncthreads();
    s[t] += x;
    __syncthreads();
  }
  if (t < nb) b[t] = s[t] - v;            // exclusive block prefix
}

__global__ void scan_add(int* __restrict__ out, int* __restrict__ cursor,
                         const int* __restrict__ bsums, int K, int total){
  int t = threadIdx.x;
  int i = blockIdx.x * 1024 + t;
  if (i < K){
    int v = out[i] + bsums[blockIdx.x];
    out[i] = v;
    cursor[i] = v;
  }
  if (i == 0) out[K] = total;
}

__global__ void scatter_kernel(const int* __restrict__ src, const int* __restrict__ dst,
                               const int* __restrict__ et, int* __restrict__ cursor,
                               int* __restrict__ ssrc){
  int e = blockIdx.x * 256 + threadIdx.x;
  int key = iclamp(dst[e] * RREL + et[e], 0, NKEY - 1);
  int p = atomicAdd(&cursor[key], 1);
  p = iclamp(p, 0, N_EDGES - 1);
  ssrc[p] = iclamp(src[e], 0, N_NODES - 1);
}

// ---------------- x (f32 [N,128]) -> packed bf16 pairs [N,64] uints ----------------

__global__ void convert_x(const float* __restrict__ x, unsigned* __restrict__ xb){
  int i = blockIdx.x * 256 + threadIdx.x;      // over N*64
  float2 v = *(const float2*)(x + (size_t)i * 2);
  xb[i] = f2bf(v.x) | (f2bf(v.y) << 16);
}

// ---------------- W (f32 [512][128]) -> Bt bf16 [128][512] ----------------

__global__ void transpose_w(const float* __restrict__ W, unsigned short* __restrict__ Bt){
  int idx = blockIdx.x * 256 + threadIdx.x;    // 65536
  int k = idx >> 7, n = idx & 127;
  Bt[n * KDIM + k] = (unsigned short)f2bf(W[idx]);
}

// ---------------- fused layer: mean -> @W -> tanh, node-per-lane, zero LDS ----------------
// Wave handles 16 nodes; lane (l15,quad) owns node n0+l15, dims quad*8+t of each 32-wide
// K-window. All 16 segments of a relation aggregate concurrently (trip = max, not sum).
// Aggregation registers double as the MFMA A-fragment after scale+pack.

__global__ __launch_bounds__(256) void fused_layer(const unsigned* __restrict__ hin,
                                                   const int* __restrict__ ssrc,
                                                   const int* __restrict__ offs,
                                                   const __bf16* __restrict__ Bt,
                                                   unsigned short* __restrict__ hout){
  int tid = threadIdx.x;
  int w = tid >> 6, lane = tid & 63;
  int l15 = lane & 15, quad = lane >> 4;
  int n0w = blockIdx.x * 64 + w * 16;
  int n = n0w + l15;                     // this lane's node
  int valid = (n < N_NODES);

  f32x4 accC[8];
  #pragma unroll
  for (int tc = 0; tc < 8; tc++) accC[tc] = (f32x4){0.f, 0.f, 0.f, 0.f};

  #pragma unroll
  for (int r = 0; r < RREL; r++){
    int ob = valid ? (n * 4 + r) : 0;
    int beg = iclamp(offs[ob], 0, N_EDGES);
    int end = iclamp(offs[ob + 1], beg, N_EDGES);
    if (!valid){ beg = 0; end = 0; }

    float ac[32];
    #pragma unroll
    for (int j = 0; j < 32; j++) ac[j] = 0.f;

    int i = beg;
    int nxt = (i < end) ? ssrc[i] : 0;          // index prefetch
    while (i < end){
      int cur = iclamp(nxt, 0, N_NODES - 1);
      i++;
      nxt = (i < end) ? ssrc[i] : 0;
      const uint4* row = (const uint4*)(hin + (size_t)cur * 64 + quad * 4);
      uint4 u0 = row[0];                        // uints quad*4 + 0..3  (dims quad*8..+7, win 0)
      uint4 u1 = row[4];                        // +16 uints            (win 1)
      uint4 u2 = row[8];                        // +32                  (win 2)
      uint4 u3 = row[12];                       // +48                  (win 3)
      ac[ 0] += bflo(u0.x); ac[ 1] += bfhi(u0.x); ac[ 2] += bflo(u0.y); ac[ 3] += bfhi(u0.y);
      ac[ 4] += bflo(u0.z); ac[ 5] += bfhi(u0.z); ac[ 6] += bflo(u0.w); ac[ 7] += bfhi(u0.w);
      ac[ 8] += bflo(u1.x); ac[ 9] += bfhi(u1.x); ac[10] += bflo(u1.y); ac[11] += bfhi(u1.y);
      ac[12] += bflo(u1.z); ac[13] += bfhi(u1.z); ac[14] += bflo(u1.w); ac[15] += bfhi(u1.w);
      ac[16] += bflo(u2.x); ac[17] += bfhi(u2.x); ac[18] += bflo(u2.y); ac[19] += bfhi(u2.y);
      ac[20] += bflo(u2.z); ac[21] += bfhi(u2.z); ac[22] += bflo(u2.w); ac[23] += bfhi(u2.w);
      ac[24] += bflo(u3.x); ac[25] += bfhi(u3.x); ac[26] += bflo(u3.y); ac[27] += bfhi(u3.y);
      ac[28] += bflo(u3.z); ac[29] += bfhi(u3.z); ac[30] += bflo(u3.w); ac[31] += bfhi(u3.w);
    }
    int cnt = end - beg;
    float sc = (cnt > 0) ? 1.0f / (float)cnt : 0.0f;

    // 4 MFMA K-steps for this relation; A-frag packed from ac
    #pragma unroll
    for (int s = 0; s < 4; s++){
      uint4 pv;
      pv.x = f2bf(ac[s * 8 + 0] * sc) | (f2bf(ac[s * 8 + 1] * sc) << 16);
      pv.y = f2bf(ac[s * 8 + 2] * sc) | (f2bf(ac[s * 8 + 3] * sc) << 16);
      pv.z = f2bf(ac[s * 8 + 4] * sc) | (f2bf(ac[s * 8 + 5] * sc) << 16);
      pv.w = f2bf(ac[s * 8 + 6] * sc) | (f2bf(ac[s * 8 + 7] * sc) << 16);
      bf16x8 af = __builtin_bit_cast(bf16x8, pv);
      const __bf16* bbase = Bt + r * 128 + s * 32 + quad * 8;
      #pragma unroll
      for (int tc = 0; tc < 8; tc++){
        bf16x8 bfr = *(const bf16x8*)(bbase + (size_t)(tc * 16 + l15) * KDIM);
        accC[tc] = __builtin_amdgcn_mfma_f32_16x16x32_bf16(af, bfr, accC[tc], 0, 0, 0);
      }
    }
  }

  // epilogue: tanh, store bf16. C layout: col=l15, row=quad*4+reg
  #pragma unroll
  for (int tc = 0; tc < 8; tc++){
    #pragma unroll
    for (int reg = 0; reg < 4; reg++){
      int n2 = n0w + quad * 4 + reg;
      if (n2 < N_NODES){
        float v = tanhf(accC[tc][reg]);
        hout[(size_t)n2 * 128 + tc * 16 + l15] = (unsigned short)f2bf(v);
      }
    }
  }
}

// ---------------- z precompute: z[n][r][2] = h2[n] . W3_r  (head linearity) ----------------
// mean(h2[src]) @ W3_r == mean(h2[src] @ W3_r): transform once per node (8 f32 per node),
// then the head gathers 8 B/edge from a 3.2 MB table (L2-resident) instead of 256 B/edge.
// One wave per node; lane holds dims (2*lane, 2*lane+1).

__global__ void compute_z(const unsigned* __restrict__ h2, const float* __restrict__ W3f,
                          float* __restrict__ zt){
  int n = blockIdx.x * 4 + (threadIdx.x >> 6);
  int lane = threadIdx.x & 63;
  unsigned u = h2[(size_t)n * 64 + lane];
  float a = bflo(u), b = bfhi(u);
  float p[8];
  #pragma unroll
  for (int r = 0; r < RREL; r++){
    float4 wv = *(const float4*)(W3f + r * 256 + lane * 4);  // W3[r, 2l, 0..1], W3[r, 2l+1, 0..1]
    p[r * 2]     = a * wv.x + b * wv.z;
    p[r * 2 + 1] = a * wv.y + b * wv.w;
  }
  #pragma unroll
  for (int m = 32; m >= 1; m >>= 1){
    #pragma unroll
    for (int j = 0; j < 8; j++) p[j] += __shfl_xor(p[j], m);
  }
  if (lane == 0){
    *(float4*)(zt + (size_t)n * 8)     = (float4){p[0], p[1], p[2], p[3]};
    *(float4*)(zt + (size_t)n * 8 + 4) = (float4){p[4], p[5], p[6], p[7]};
  }
}

// ---------------- head: thread per (node,rel) key; mean of z[src,rel] -> reduce -> softmax ----

__global__ void fused_head2(const float* __restrict__ zt,
                            const int* __restrict__ ssrc,
                            const int* __restrict__ offs,
                            float* __restrict__ out){
  int k = blockIdx.x * 256 + threadIdx.x;
  if (k >= NKEY) return;                  // whole waves exit; 4-groups stay intact
  int r = k & 3;
  int beg = iclamp(offs[k], 0, N_EDGES);
  int end = iclamp(offs[k + 1], beg, N_EDGES);
  float a0 = 0.f, a1 = 0.f, b0 = 0.f, b1 = 0.f, c0 = 0.f, c1 = 0.f, d0 = 0.f, d1 = 0.f;
  int i = beg;
  for (; i + 4 <= end; i += 4){
    int s0 = iclamp(ssrc[i],     0, N_NODES - 1);
    int s1 = iclamp(ssrc[i + 1], 0, N_NODES - 1);
    int s2 = iclamp(ssrc[i + 2], 0, N_NODES - 1);
    int s3 = iclamp(ssrc[i + 3], 0, N_NODES - 1);
    float2 v0 = *(const float2*)(zt + (size_t)s0 * 8 + r * 2);
    float2 v1 = *(const float2*)(zt + (size_t)s1 * 8 + r * 2);
    float2 v2 = *(const float2*)(zt + (size_t)s2 * 8 + r * 2);
    float2 v3 = *(const float2*)(zt + (size_t)s3 * 8 + r * 2);
    a0 += v0.x; a1 += v0.y;
    b0 += v1.x; b1 += v1.y;
    c0 += v2.x; c1 += v2.y;
    d0 += v3.x; d1 += v3.y;
  }
  for (; i < end; i++){
    int s = iclamp(ssrc[i], 0, N_NODES - 1);
    float2 v = *(const float2*)(zt + (size_t)s * 8 + r * 2);
    a0 += v.x; a1 += v.y;
  }
  int cnt = end - beg;
  float sc = (cnt > 0) ? 1.0f / (float)cnt : 0.0f;
  float dA = (a0 + b0 + c0 + d0) * sc;
  float dB = (a1 + b1 + c1 + d1) * sc;
  // sum the 4 relations (4 consecutive lanes of this wave)
  dA += __shfl_xor(dA, 1); dB += __shfl_xor(dB, 1);
  dA += __shfl_xor(dA, 2); dB += __shfl_xor(dB, 2);
  if (r == 0){
    int n = k >> 2;
    float mx = fmaxf(dA, dB);
    float e0 = __expf(dA - mx), e1 = __expf(dB - mx);
    float inv = 1.0f / (e0 + e1);
    *(float2*)(out + 2 * n) = (float2){e0 * inv, e1 * inv};            // softmax [N,2]
    *(float2*)(out + 2 * N_NODES + 2 * n) = (float2){dA, dB};          // logits  [N,2]
  }
}

// ---------------- launch ----------------

extern "C" void kernel_launch(void* const* d_in, const int* in_sizes, int n_in,
                              void* d_out, int out_size, void* d_ws, size_t ws_size,
                              hipStream_t stream){
  const float* x  = (const float*)d_in[0];
  const int* ei   = (const int*)d_in[1];
  const int* et   = (const int*)d_in[2];
  const float* W1 = (const float*)d_in[3];
  const float* W2 = (const float*)d_in[4];
  const float* W3 = (const float*)d_in[5];
  float* out = (float*)d_out;
  const int* src = ei;
  const int* dst = ei + N_EDGES;

  // workspace layout: ~61 MB total
  char* p = (char*)d_ws;
  auto alloc = [&](size_t bytes) -> char* {
    char* q = p; p += (bytes + 63) & ~(size_t)63; return q;
  };
  int* counts = (int*)alloc((size_t)NKEY * 4);          // reused as cursor
  int* cursor = counts;
  int* offs   = (int*)alloc((size_t)(NKEY + 1) * 4);
  int* bsums  = (int*)alloc(1024 * 4);
  int* ssrc   = (int*)alloc((size_t)N_EDGES * 4);
  unsigned short* Bt = (unsigned short*)alloc((size_t)DDIM * KDIM * 2);
  unsigned short* h1 = (unsigned short*)alloc((size_t)N_NODES * DDIM * 2);
  unsigned short* h2 = (unsigned short*)alloc((size_t)N_NODES * DDIM * 2);
  unsigned* xb = (unsigned*)h2;   // x-as-bf16 lives in h2's slot (dead until layer-2 output)
  float* zt = (float*)h1;         // z table aliases h1 (dead after layer-2 reads it)

  // sort edges by (dst, relation)
  hipMemsetAsync(counts, 0, (size_t)NKEY * 4, stream);
  hist_kernel<<<N_EDGES / 256, 256, 0, stream>>>(dst, et, counts);
  int nb = (NKEY + 1023) / 1024;  // 391
  scan_local<<<nb, 1024, 0, stream>>>(counts, offs, bsums, NKEY);
  scan_sums<<<1, 1024, 0, stream>>>(bsums, nb);
  scan_add<<<nb, 1024, 0, stream>>>(offs, cursor, bsums, NKEY, N_EDGES);
  scatter_kernel<<<N_EDGES / 256, 256, 0, stream>>>(src, dst, et, cursor, ssrc);

  int fgrid = (N_NODES + 63) / 64;  // 1563

  // layer 1: x -> packed bf16, agg -> @W1 -> tanh -> h1
  convert_x<<<(N_NODES * 64) / 256, 256, 0, stream>>>(x, xb);
  transpose_w<<<(DDIM * KDIM) / 256, 256, 0, stream>>>(W1, Bt);
  fused_layer<<<fgrid, 256, 0, stream>>>(xb, ssrc, offs, (const __bf16*)Bt, h1);
  // layer 2: h1 -> h2 (xb dead from here on)
  transpose_w<<<(DDIM * KDIM) / 256, 256, 0, stream>>>(W2, Bt);
  fused_layer<<<fgrid, 256, 0, stream>>>((const unsigned*)h1, ssrc, offs, (const __bf16*)Bt, h2);
  // layer 3 head: z = h2 @ W3 per relation (8 f32/node), then 8 B/edge gather + softmax
  compute_z<<<N_NODES / 4, 256, 0, stream>>>((const unsigned*)h2, W3, zt);
  fused_head2<<<(NKEY + 255) / 256, 256, 0, stream>>>(zt, ssrc, offs, out);
}

// Round 2
// 748.852 us; speedup vs baseline: 1.0914x; 1.0068x over previous
//
#include <hip/hip_runtime.h>
#include <math.h>

#define N_NODES 100000
#define N_EDGES 1600000
#define RREL 4
#define DDIM 128
#define KDIM 512      // RREL*DDIM
#define NKEY 400000   // N_NODES*RREL

typedef __bf16 bf16x8 __attribute__((ext_vector_type(8)));
typedef float f32x4 __attribute__((ext_vector_type(4)));

__device__ __forceinline__ float bflo(unsigned u){ return __builtin_bit_cast(float, u << 16); }
__device__ __forceinline__ float bfhi(unsigned u){ return __builtin_bit_cast(float, u & 0xffff0000u); }
__device__ __forceinline__ unsigned f2bf(float f){
  unsigned u = __builtin_bit_cast(unsigned, f);
  return (u + 0x7fffu + ((u >> 16) & 1u)) >> 16;   // RNE, finite inputs
}
__device__ __forceinline__ int iclamp(int v, int lo, int hi){
  return v < lo ? lo : (v > hi ? hi : v);
}

// ---------------- counting sort of edges by key = dst*4 + et ----------------

__global__ void hist_kernel(const int* __restrict__ dst, const int* __restrict__ et,
                            int* __restrict__ counts){
  int e = blockIdx.x * 256 + threadIdx.x;
  int key = iclamp(dst[e] * RREL + et[e], 0, NKEY - 1);
  atomicAdd(&counts[key], 1);
}

__global__ void scan_local(const int* __restrict__ in, int* __restrict__ out,
                           int* __restrict__ bsums, int K){
  __shared__ int s[1024];
  int t = threadIdx.x;
  int i = blockIdx.x * 1024 + t;
  int v = (i < K) ? in[i] : 0;
  s[t] = v; __syncthreads();
  for (int off = 1; off < 1024; off <<= 1){
    int x = (t >= off) ? s[t - off] : 0;
    __syncthreads();
    s[t] += x;
    __syncthreads();
  }
  if (i < K) out[i] = s[t] - v;           // exclusive within block
  if (t == 1023) bsums[blockIdx.x] = s[t];
}

__global__ void scan_sums(int* __restrict__ b, int nb){
  __shared__ int s[1024];
  int t = threadIdx.x;
  int v = (t < nb) ? b[t] : 0;
  s[t] = v; __syncthreads();
  for (int off = 1; off < 1024; off <<= 1){
    int x = (t >= off) ? s[t - off] : 0;
    __syncthreads();
    s[t] += x;
    __syncthreads();
  }
  if (t < nb) b[t] = s[t] - v;            // exclusive block prefix
}

__global__ void scan_add(int* __restrict__ out, int* __restrict__ cursor,
                         const int* __restrict__ bsums, int K, int total){
  int t = threadIdx.x;
  int i = blockIdx.x * 1024 + t;
  if (i < K){
    int v = out[i] + bsums[blockIdx.x];
    out[i] = v;
    cursor[i] = v;
  }
  if (i == 0) out[K] = total;
}

__global__ void scatter_kernel(const int* __restrict__ src, const int* __restrict__ dst,
                               const int* __restrict__ et, int* __restrict__ cursor,
                               int* __restrict__ ssrc){
  int e = blockIdx.x * 256 + threadIdx.x;
  int key = iclamp(dst[e] * RREL + et[e], 0, NKEY - 1);
  int p = atomicAdd(&cursor[key], 1);
  p = iclamp(p, 0, N_EDGES - 1);
  ssrc[p] = iclamp(src[e], 0, N_NODES - 1);
}

// ---------------- x (f32 [N,128]) -> packed bf16 pairs [N,64] uints ----------------

__global__ void convert_x(const float* __restrict__ x, unsigned* __restrict__ xb){
  int i = blockIdx.x * 256 + threadIdx.x;      // over N*64
  float2 v = *(const float2*)(x + (size_t)i * 2);
  xb[i] = f2bf(v.x) | (f2bf(v.y) << 16);
}

// ---------------- W (f32 [512][128]) -> Bt bf16 [128][512] ----------------

__global__ void transpose_w(const float* __restrict__ W, unsigned short* __restrict__ Bt){
  int idx = blockIdx.x * 256 + threadIdx.x;    // 65536
  int k = idx >> 7, n = idx & 127;
  Bt[n * KDIM + k] = (unsigned short)f2bf(W[idx]);
}

// ---------------- fused layer: mean -> @W -> tanh, node-per-lane, zero LDS ----------------
// Wave handles 16 nodes; lane (l15,quad) owns node n0+l15, dims quad*8+t of each 32-wide
// K-window. All 16 segments of a relation aggregate concurrently (trip = max, not sum).
// 2-deep software pipeline: row loads for edge i+1 are issued before accumulating edge i
// (index prefetched 2 ahead), so the wave waits only on loads issued one iteration earlier.

__global__ __launch_bounds__(256) void fused_layer(const unsigned* __restrict__ hin,
                                                   const int* __restrict__ ssrc,
                                                   const int* __restrict__ offs,
                                                   const __bf16* __restrict__ Bt,
                                                   unsigned short* __restrict__ hout){
  int tid = threadIdx.x;
  int w = tid >> 6, lane = tid & 63;
  int l15 = lane & 15, quad = lane >> 4;
  int n0w = blockIdx.x * 64 + w * 16;
  int n = n0w + l15;                     // this lane's node
  int valid = (n < N_NODES);

  f32x4 accC[8];
  #pragma unroll
  for (int tc = 0; tc < 8; tc++) accC[tc] = (f32x4){0.f, 0.f, 0.f, 0.f};

  #pragma unroll
  for (int r = 0; r < RREL; r++){
    int ob = valid ? (n * 4 + r) : 0;
    int beg = iclamp(offs[ob], 0, N_EDGES);
    int end = iclamp(offs[ob + 1], beg, N_EDGES);
    if (!valid){ beg = 0; end = 0; }

    float ac[32];
    #pragma unroll
    for (int j = 0; j < 32; j++) ac[j] = 0.f;

    if (beg < end){
      int cur = iclamp(ssrc[beg], 0, N_NODES - 1);
      int j = beg + 1;
      int nxtidx = (j < end) ? ssrc[j] : 0;      // index 1 ahead of the b-loads
      const uint4* rowa = (const uint4*)(hin + (size_t)cur * 64 + quad * 4);
      uint4 a0 = rowa[0], a1 = rowa[4], a2 = rowa[8], a3 = rowa[12];
      while (j < end){
        int thisidx = iclamp(nxtidx, 0, N_NODES - 1);
        nxtidx = (j + 1 < end) ? ssrc[j + 1] : 0;
        const uint4* rowb = (const uint4*)(hin + (size_t)thisidx * 64 + quad * 4);
        uint4 b0 = rowb[0], b1 = rowb[4], b2 = rowb[8], b3 = rowb[12];
        // consume edge j-1 (loads already ~1 iteration old)
        ac[ 0] += bflo(a0.x); ac[ 1] += bfhi(a0.x); ac[ 2] += bflo(a0.y); ac[ 3] += bfhi(a0.y);
        ac[ 4] += bflo(a0.z); ac[ 5] += bfhi(a0.z); ac[ 6] += bflo(a0.w); ac[ 7] += bfhi(a0.w);
        ac[ 8] += bflo(a1.x); ac[ 9] += bfhi(a1.x); ac[10] += bflo(a1.y); ac[11] += bfhi(a1.y);
        ac[12] += bflo(a1.z); ac[13] += bfhi(a1.z); ac[14] += bflo(a1.w); ac[15] += bfhi(a1.w);
        ac[16] += bflo(a2.x); ac[17] += bfhi(a2.x); ac[18] += bflo(a2.y); ac[19] += bfhi(a2.y);
        ac[20] += bflo(a2.z); ac[21] += bfhi(a2.z); ac[22] += bflo(a2.w); ac[23] += bfhi(a2.w);
        ac[24] += bflo(a3.x); ac[25] += bfhi(a3.x); ac[26] += bflo(a3.y); ac[27] += bfhi(a3.y);
        ac[28] += bflo(a3.z); ac[29] += bfhi(a3.z); ac[30] += bflo(a3.w); ac[31] += bfhi(a3.w);
        a0 = b0; a1 = b1; a2 = b2; a3 = b3;
        j++;
      }
      // last edge
      ac[ 0] += bflo(a0.x); ac[ 1] += bfhi(a0.x); ac[ 2] += bflo(a0.y); ac[ 3] += bfhi(a0.y);
      ac[ 4] += bflo(a0.z); ac[ 5] += bfhi(a0.z); ac[ 6] += bflo(a0.w); ac[ 7] += bfhi(a0.w);
      ac[ 8] += bflo(a1.x); ac[ 9] += bfhi(a1.x); ac[10] += bflo(a1.y); ac[11] += bfhi(a1.y);
      ac[12] += bflo(a1.z); ac[13] += bfhi(a1.z); ac[14] += bflo(a1.w); ac[15] += bfhi(a1.w);
      ac[16] += bflo(a2.x); ac[17] += bfhi(a2.x); ac[18] += bflo(a2.y); ac[19] += bfhi(a2.y);
      ac[20] += bflo(a2.z); ac[21] += bfhi(a2.z); ac[22] += bflo(a2.w); ac[23] += bfhi(a2.w);
      ac[24] += bflo(a3.x); ac[25] += bfhi(a3.x); ac[26] += bflo(a3.y); ac[27] += bfhi(a3.y);
      ac[28] += bflo(a3.z); ac[29] += bfhi(a3.z); ac[30] += bflo(a3.w); ac[31] += bfhi(a3.w);
    }
    int cnt = end - beg;
    float sc = (cnt > 0) ? 1.0f / (float)cnt : 0.0f;

    // 4 MFMA K-steps for this relation; A-frag packed from ac
    #pragma unroll
    for (int s = 0; s < 4; s++){
      uint4 pv;
      pv.x = f2bf(ac[s * 8 + 0] * sc) | (f2bf(ac[s * 8 + 1] * sc) << 16);
      pv.y = f2bf(ac[s * 8 + 2] * sc) | (f2bf(ac[s * 8 + 3] * sc) << 16);
      pv.z = f2bf(ac[s * 8 + 4] * sc) | (f2bf(ac[s * 8 + 5] * sc) << 16);
      pv.w = f2bf(ac[s * 8 + 6] * sc) | (f2bf(ac[s * 8 + 7] * sc) << 16);
      bf16x8 af = __builtin_bit_cast(bf16x8, pv);
      const __bf16* bbase = Bt + r * 128 + s * 32 + quad * 8;
      #pragma unroll
      for (int tc = 0; tc < 8; tc++){
        bf16x8 bfr = *(const bf16x8*)(bbase + (size_t)(tc * 16 + l15) * KDIM);
        accC[tc] = __builtin_amdgcn_mfma_f32_16x16x32_bf16(af, bfr, accC[tc], 0, 0, 0);
      }
    }
  }

  // epilogue: tanh, store bf16. C layout: col=l15, row=quad*4+reg
  #pragma unroll
  for (int tc = 0; tc < 8; tc++){
    #pragma unroll
    for (int reg = 0; reg < 4; reg++){
      int n2 = n0w + quad * 4 + reg;
      if (n2 < N_NODES){
        float v = tanhf(accC[tc][reg]);
        hout[(size_t)n2 * 128 + tc * 16 + l15] = (unsigned short)f2bf(v);
      }
    }
  }
}

// ---------------- z precompute: z[n][r][2] = h2[n] . W3_r  (head linearity) ----------------
// mean(h2[src]) @ W3_r == mean(h2[src] @ W3_r): transform once per node (8 f32 per node),
// then the head gathers 8 B/edge from a 3.2 MB table (L2-resident) instead of 256 B/edge.
// One wave per node; lane holds dims (2*lane, 2*lane+1).

__global__ void compute_z(const unsigned* __restrict__ h2, const float* __restrict__ W3f,
                          float* __restrict__ zt){
  int n = blockIdx.x * 4 + (threadIdx.x >> 6);
  int lane = threadIdx.x & 63;
  unsigned u = h2[(size_t)n * 64 + lane];
  float a = bflo(u), b = bfhi(u);
  float p[8];
  #pragma unroll
  for (int r = 0; r < RREL; r++){
    float4 wv = *(const float4*)(W3f + r * 256 + lane * 4);  // W3[r, 2l, 0..1], W3[r, 2l+1, 0..1]
    p[r * 2]     = a * wv.x + b * wv.z;
    p[r * 2 + 1] = a * wv.y + b * wv.w;
  }
  #pragma unroll
  for (int m = 32; m >= 1; m >>= 1){
    #pragma unroll
    for (int j = 0; j < 8; j++) p[j] += __shfl_xor(p[j], m);
  }
  if (lane == 0){
    *(float4*)(zt + (size_t)n * 8)     = (float4){p[0], p[1], p[2], p[3]};
    *(float4*)(zt + (size_t)n * 8 + 4) = (float4){p[4], p[5], p[6], p[7]};
  }
}

// ---------------- head: thread per (node,rel) key; mean of z[src,rel] -> reduce -> softmax ----

__global__ void fused_head2(const float* __restrict__ zt,
                            const int* __restrict__ ssrc,
                            const int* __restrict__ offs,
                            float* __restrict__ out){
  int k = blockIdx.x * 256 + threadIdx.x;
  if (k >= NKEY) return;                  // whole waves exit; 4-groups stay intact
  int r = k & 3;
  int beg = iclamp(offs[k], 0, N_EDGES);
  int end = iclamp(offs[k + 1], beg, N_EDGES);
  float a0 = 0.f, a1 = 0.f, b0 = 0.f, b1 = 0.f, c0 = 0.f, c1 = 0.f, d0 = 0.f, d1 = 0.f;
  int i = beg;
  for (; i + 4 <= end; i += 4){
    int s0 = iclamp(ssrc[i],     0, N_NODES - 1);
    int s1 = iclamp(ssrc[i + 1], 0, N_NODES - 1);
    int s2 = iclamp(ssrc[i + 2], 0, N_NODES - 1);
    int s3 = iclamp(ssrc[i + 3], 0, N_NODES - 1);
    float2 v0 = *(const float2*)(zt + (size_t)s0 * 8 + r * 2);
    float2 v1 = *(const float2*)(zt + (size_t)s1 * 8 + r * 2);
    float2 v2 = *(const float2*)(zt + (size_t)s2 * 8 + r * 2);
    float2 v3 = *(const float2*)(zt + (size_t)s3 * 8 + r * 2);
    a0 += v0.x; a1 += v0.y;
    b0 += v1.x; b1 += v1.y;
    c0 += v2.x; c1 += v2.y;
    d0 += v3.x; d1 += v3.y;
  }
  for (; i < end; i++){
    int s = iclamp(ssrc[i], 0, N_NODES - 1);
    float2 v = *(const float2*)(zt + (size_t)s * 8 + r * 2);
    a0 += v.x; a1 += v.y;
  }
  int cnt = end - beg;
  float sc = (cnt > 0) ? 1.0f / (float)cnt : 0.0f;
  float dA = (a0 + b0 + c0 + d0) * sc;
  float dB = (a1 + b1 + c1 + d1) * sc;
  // sum the 4 relations (4 consecutive lanes of this wave)
  dA += __shfl_xor(dA, 1); dB += __shfl_xor(dB, 1);
  dA += __shfl_xor(dA, 2); dB += __shfl_xor(dB, 2);
  if (r == 0){
    int n = k >> 2;
    float mx = fmaxf(dA, dB);
    float e0 = __expf(dA - mx), e1 = __expf(dB - mx);
    float inv = 1.0f / (e0 + e1);
    *(float2*)(out + 2 * n) = (float2){e0 * inv, e1 * inv};            // softmax [N,2]
    *(float2*)(out + 2 * N_NODES + 2 * n) = (float2){dA, dB};          // logits  [N,2]
  }
}

// ---------------- launch ----------------

extern "C" void kernel_launch(void* const* d_in, const int* in_sizes, int n_in,
                              void* d_out, int out_size, void* d_ws, size_t ws_size,
                              hipStream_t stream){
  const float* x  = (const float*)d_in[0];
  const int* ei   = (const int*)d_in[1];
  const int* et   = (const int*)d_in[2];
  const float* W1 = (const float*)d_in[3];
  const float* W2 = (const float*)d_in[4];
  const float* W3 = (const float*)d_in[5];
  float* out = (float*)d_out;
  const int* src = ei;
  const int* dst = ei + N_EDGES;

  // workspace layout: ~61 MB total
  char* p = (char*)d_ws;
  auto alloc = [&](size_t bytes) -> char* {
    char* q = p; p += (bytes + 63) & ~(size_t)63; return q;
  };
  int* counts = (int*)alloc((size_t)NKEY * 4);          // reused as cursor
  int* cursor = counts;
  int* offs   = (int*)alloc((size_t)(NKEY + 1) * 4);
  int* bsums  = (int*)alloc(1024 * 4);
  int* ssrc   = (int*)alloc((size_t)N_EDGES * 4);
  unsigned short* Bt = (unsigned short*)alloc((size_t)DDIM * KDIM * 2);
  unsigned short* h1 = (unsigned short*)alloc((size_t)N_NODES * DDIM * 2);
  unsigned short* h2 = (unsigned short*)alloc((size_t)N_NODES * DDIM * 2);
  unsigned* xb = (unsigned*)h2;   // x-as-bf16 lives in h2's slot (dead until layer-2 output)
  float* zt = (float*)h1;         // z table aliases h1 (dead after layer-2 reads it)

  // sort edges by (dst, relation)
  hipMemsetAsync(counts, 0, (size_t)NKEY * 4, stream);
  hist_kernel<<<N_EDGES / 256, 256, 0, stream>>>(dst, et, counts);
  int nb = (NKEY + 1023) / 1024;  // 391
  scan_local<<<nb, 1024, 0, stream>>>(counts, offs, bsums, NKEY);
  scan_sums<<<1, 1024, 0, stream>>>(bsums, nb);
  scan_add<<<nb, 1024, 0, stream>>>(offs, cursor, bsums, NKEY, N_EDGES);
  scatter_kernel<<<N_EDGES / 256, 256, 0, stream>>>(src, dst, et, cursor, ssrc);

  int fgrid = (N_NODES + 63) / 64;  // 1563

  // layer 1: x -> packed bf16, agg -> @W1 -> tanh -> h1
  convert_x<<<(N_NODES * 64) / 256, 256, 0, stream>>>(x, xb);
  transpose_w<<<(DDIM * KDIM) / 256, 256, 0, stream>>>(W1, Bt);
  fused_layer<<<fgrid, 256, 0, stream>>>(xb, ssrc, offs, (const __bf16*)Bt, h1);
  // layer 2: h1 -> h2 (xb dead from here on)
  transpose_w<<<(DDIM * KDIM) / 256, 256, 0, stream>>>(W2, Bt);
  fused_layer<<<fgrid, 256, 0, stream>>>((const unsigned*)h1, ssrc, offs, (const __bf16*)Bt, h2);
  // layer 3 head: z = h2 @ W3 per relation (8 f32/node), then 8 B/edge gather + softmax
  compute_z<<<N_NODES / 4, 256, 0, stream>>>((const unsigned*)h2, W3, zt);
  fused_head2<<<(NKEY + 255) / 256, 256, 0, stream>>>(zt, ssrc, offs, out);
}

// Round 3
// 741.157 us; speedup vs baseline: 1.1027x; 1.0104x over previous
//
#include <hip/hip_runtime.h>
#include <math.h>

#define N_NODES 100000
#define N_EDGES 1600000
#define RREL 4
#define DDIM 128
#define KDIM 512      // RREL*DDIM
#define NKEY 400000   // N_NODES*RREL

typedef __bf16 bf16x8 __attribute__((ext_vector_type(8)));
typedef float f32x4 __attribute__((ext_vector_type(4)));

__device__ __forceinline__ float bflo(unsigned u){ return __builtin_bit_cast(float, u << 16); }
__device__ __forceinline__ float bfhi(unsigned u){ return __builtin_bit_cast(float, u & 0xffff0000u); }
__device__ __forceinline__ unsigned f2bf(float f){
  unsigned u = __builtin_bit_cast(unsigned, f);
  return (u + 0x7fffu + ((u >> 16) & 1u)) >> 16;   // RNE, finite inputs
}
__device__ __forceinline__ int iclamp(int v, int lo, int hi){
  return v < lo ? lo : (v > hi ? hi : v);
}

// ---------------- counting sort of edges by key = dst*4 + et ----------------

__global__ void hist_kernel(const int* __restrict__ dst, const int* __restrict__ et,
                            int* __restrict__ counts){
  int e = blockIdx.x * 256 + threadIdx.x;
  int key = iclamp(dst[e] * RREL + et[e], 0, NKEY - 1);
  atomicAdd(&counts[key], 1);
}

__global__ void scan_local(const int* __restrict__ in, int* __restrict__ out,
                           int* __restrict__ bsums, int K){
  __shared__ int s[1024];
  int t = threadIdx.x;
  int i = blockIdx.x * 1024 + t;
  int v = (i < K) ? in[i] : 0;
  s[t] = v; __syncthreads();
  for (int off = 1; off < 1024; off <<= 1){
    int x = (t >= off) ? s[t - off] : 0;
    __syncthreads();
    s[t] += x;
    __syncthreads();
  }
  if (i < K) out[i] = s[t] - v;           // exclusive within block
  if (t == 1023) bsums[blockIdx.x] = s[t];
}

__global__ void scan_sums(int* __restrict__ b, int nb){
  __shared__ int s[1024];
  int t = threadIdx.x;
  int v = (t < nb) ? b[t] : 0;
  s[t] = v; __syncthreads();
  for (int off = 1; off < 1024; off <<= 1){
    int x = (t >= off) ? s[t - off] : 0;
    __syncthreads();
    s[t] += x;
    __syncthreads();
  }
  if (t < nb) b[t] = s[t] - v;            // exclusive block prefix
}

__global__ void scan_add(int* __restrict__ out, int* __restrict__ cursor,
                         const int* __restrict__ bsums, int K, int total){
  int t = threadIdx.x;
  int i = blockIdx.x * 1024 + t;
  if (i < K){
    int v = out[i] + bsums[blockIdx.x];
    out[i] = v;
    cursor[i] = v;
  }
  if (i == 0) out[K] = total;
}

__global__ void scatter_kernel(const int* __restrict__ src, const int* __restrict__ dst,
                               const int* __restrict__ et, int* __restrict__ cursor,
                               int* __restrict__ ssrc){
  int e = blockIdx.x * 256 + threadIdx.x;
  int key = iclamp(dst[e] * RREL + et[e], 0, NKEY - 1);
  int p = atomicAdd(&cursor[key], 1);
  p = iclamp(p, 0, N_EDGES - 1);
  ssrc[p] = iclamp(src[e], 0, N_NODES - 1);
}

// ---------------- x (f32 [N,128]) -> packed bf16 pairs [N,64] uints ----------------

__global__ void convert_x(const float* __restrict__ x, unsigned* __restrict__ xb){
  int i = blockIdx.x * 256 + threadIdx.x;      // over N*64
  float2 v = *(const float2*)(x + (size_t)i * 2);
  xb[i] = f2bf(v.x) | (f2bf(v.y) << 16);
}

// ---------------- W (f32 [512][128]) -> Bt bf16 [128][512] ----------------

__global__ void transpose_w(const float* __restrict__ W, unsigned short* __restrict__ Bt){
  int idx = blockIdx.x * 256 + threadIdx.x;    // 65536
  int k = idx >> 7, n = idx & 127;
  Bt[n * KDIM + k] = (unsigned short)f2bf(W[idx]);
}

// ---------------- fused layer: mean -> @W -> tanh, node-per-lane, zero LDS ----------------
// Wave handles 16 nodes; lane (l15,quad) owns node n0+l15, dims quad*8+t of each 32-wide
// K-window. 2-deep software pipeline ENFORCED by sched_barrier(0): the row loads for
// edge i+1 are fenced above the accumulate of edge i, so the compiler cannot sink them
// below the s_waitcnt (it did in the un-fenced version: VGPR stayed 76, dur unchanged).

__global__ __launch_bounds__(256) void fused_layer(const unsigned* __restrict__ hin,
                                                   const int* __restrict__ ssrc,
                                                   const int* __restrict__ offs,
                                                   const __bf16* __restrict__ Bt,
                                                   unsigned short* __restrict__ hout){
  int tid = threadIdx.x;
  int w = tid >> 6, lane = tid & 63;
  int l15 = lane & 15, quad = lane >> 4;
  int n0w = blockIdx.x * 64 + w * 16;
  int n = n0w + l15;                     // this lane's node
  int valid = (n < N_NODES);

  f32x4 accC[8];
  #pragma unroll
  for (int tc = 0; tc < 8; tc++) accC[tc] = (f32x4){0.f, 0.f, 0.f, 0.f};

  #pragma unroll
  for (int r = 0; r < RREL; r++){
    int ob = valid ? (n * 4 + r) : 0;
    int beg = iclamp(offs[ob], 0, N_EDGES);
    int end = iclamp(offs[ob + 1], beg, N_EDGES);
    if (!valid){ beg = 0; end = 0; }

    float ac[32];
    #pragma unroll
    for (int j = 0; j < 32; j++) ac[j] = 0.f;

    if (beg < end){
      int cur = iclamp(ssrc[beg], 0, N_NODES - 1);
      int j = beg + 1;
      int nxtidx = (j < end) ? ssrc[j] : 0;      // index 1 ahead of the b-loads
      const uint4* rowa = (const uint4*)(hin + (size_t)cur * 64 + quad * 4);
      uint4 a0 = rowa[0], a1 = rowa[4], a2 = rowa[8], a3 = rowa[12];
      while (j < end){
        int thisidx = iclamp(nxtidx, 0, N_NODES - 1);
        nxtidx = (j + 1 < end) ? ssrc[j + 1] : 0;
        const uint4* rowb = (const uint4*)(hin + (size_t)thisidx * 64 + quad * 4);
        uint4 b0 = rowb[0], b1 = rowb[4], b2 = rowb[8], b3 = rowb[12];
        // fence: loads above may NOT be sunk below; accumulate below may NOT be hoisted
        __builtin_amdgcn_sched_barrier(0);
        // consume edge j-1 (loads issued one iteration ago)
        ac[ 0] += bflo(a0.x); ac[ 1] += bfhi(a0.x); ac[ 2] += bflo(a0.y); ac[ 3] += bfhi(a0.y);
        ac[ 4] += bflo(a0.z); ac[ 5] += bfhi(a0.z); ac[ 6] += bflo(a0.w); ac[ 7] += bfhi(a0.w);
        ac[ 8] += bflo(a1.x); ac[ 9] += bfhi(a1.x); ac[10] += bflo(a1.y); ac[11] += bfhi(a1.y);
        ac[12] += bflo(a1.z); ac[13] += bfhi(a1.z); ac[14] += bflo(a1.w); ac[15] += bfhi(a1.w);
        ac[16] += bflo(a2.x); ac[17] += bfhi(a2.x); ac[18] += bflo(a2.y); ac[19] += bfhi(a2.y);
        ac[20] += bflo(a2.z); ac[21] += bfhi(a2.z); ac[22] += bflo(a2.w); ac[23] += bfhi(a2.w);
        ac[24] += bflo(a3.x); ac[25] += bfhi(a3.x); ac[26] += bflo(a3.y); ac[27] += bfhi(a3.y);
        ac[28] += bflo(a3.z); ac[29] += bfhi(a3.z); ac[30] += bflo(a3.w); ac[31] += bfhi(a3.w);
        a0 = b0; a1 = b1; a2 = b2; a3 = b3;
        j++;
      }
      // last edge
      ac[ 0] += bflo(a0.x); ac[ 1] += bfhi(a0.x); ac[ 2] += bflo(a0.y); ac[ 3] += bfhi(a0.y);
      ac[ 4] += bflo(a0.z); ac[ 5] += bfhi(a0.z); ac[ 6] += bflo(a0.w); ac[ 7] += bfhi(a0.w);
      ac[ 8] += bflo(a1.x); ac[ 9] += bfhi(a1.x); ac[10] += bflo(a1.y); ac[11] += bfhi(a1.y);
      ac[12] += bflo(a1.z); ac[13] += bfhi(a1.z); ac[14] += bflo(a1.w); ac[15] += bfhi(a1.w);
      ac[16] += bflo(a2.x); ac[17] += bfhi(a2.x); ac[18] += bflo(a2.y); ac[19] += bfhi(a2.y);
      ac[20] += bflo(a2.z); ac[21] += bfhi(a2.z); ac[22] += bflo(a2.w); ac[23] += bfhi(a2.w);
      ac[24] += bflo(a3.x); ac[25] += bfhi(a3.x); ac[26] += bflo(a3.y); ac[27] += bfhi(a3.y);
      ac[28] += bflo(a3.z); ac[29] += bfhi(a3.z); ac[30] += bflo(a3.w); ac[31] += bfhi(a3.w);
    }
    int cnt = end - beg;
    float sc = (cnt > 0) ? 1.0f / (float)cnt : 0.0f;

    // 4 MFMA K-steps for this relation; A-frag packed from ac
    #pragma unroll
    for (int s = 0; s < 4; s++){
      uint4 pv;
      pv.x = f2bf(ac[s * 8 + 0] * sc) | (f2bf(ac[s * 8 + 1] * sc) << 16);
      pv.y = f2bf(ac[s * 8 + 2] * sc) | (f2bf(ac[s * 8 + 3] * sc) << 16);
      pv.z = f2bf(ac[s * 8 + 4] * sc) | (f2bf(ac[s * 8 + 5] * sc) << 16);
      pv.w = f2bf(ac[s * 8 + 6] * sc) | (f2bf(ac[s * 8 + 7] * sc) << 16);
      bf16x8 af = __builtin_bit_cast(bf16x8, pv);
      const __bf16* bbase = Bt + r * 128 + s * 32 + quad * 8;
      #pragma unroll
      for (int tc = 0; tc < 8; tc++){
        bf16x8 bfr = *(const bf16x8*)(bbase + (size_t)(tc * 16 + l15) * KDIM);
        accC[tc] = __builtin_amdgcn_mfma_f32_16x16x32_bf16(af, bfr, accC[tc], 0, 0, 0);
      }
    }
  }

  // epilogue: tanh, store bf16. C layout: col=l15, row=quad*4+reg
  #pragma unroll
  for (int tc = 0; tc < 8; tc++){
    #pragma unroll
    for (int reg = 0; reg < 4; reg++){
      int n2 = n0w + quad * 4 + reg;
      if (n2 < N_NODES){
        float v = tanhf(accC[tc][reg]);
        hout[(size_t)n2 * 128 + tc * 16 + l15] = (unsigned short)f2bf(v);
      }
    }
  }
}

// ---------------- z precompute: z[n][r][2] = h2[n] . W3_r  (head linearity) ----------------
// mean(h2[src]) @ W3_r == mean(h2[src] @ W3_r): transform once per node (8 f32 per node),
// then the head gathers 8 B/edge from a 3.2 MB table (L2-resident) instead of 256 B/edge.
// One wave per node; lane holds dims (2*lane, 2*lane+1).

__global__ void compute_z(const unsigned* __restrict__ h2, const float* __restrict__ W3f,
                          float* __restrict__ zt){
  int n = blockIdx.x * 4 + (threadIdx.x >> 6);
  int lane = threadIdx.x & 63;
  unsigned u = h2[(size_t)n * 64 + lane];
  float a = bflo(u), b = bfhi(u);
  float p[8];
  #pragma unroll
  for (int r = 0; r < RREL; r++){
    float4 wv = *(const float4*)(W3f + r * 256 + lane * 4);  // W3[r, 2l, 0..1], W3[r, 2l+1, 0..1]
    p[r * 2]     = a * wv.x + b * wv.z;
    p[r * 2 + 1] = a * wv.y + b * wv.w;
  }
  #pragma unroll
  for (int m = 32; m >= 1; m >>= 1){
    #pragma unroll
    for (int j = 0; j < 8; j++) p[j] += __shfl_xor(p[j], m);
  }
  if (lane == 0){
    *(float4*)(zt + (size_t)n * 8)     = (float4){p[0], p[1], p[2], p[3]};
    *(float4*)(zt + (size_t)n * 8 + 4) = (float4){p[4], p[5], p[6], p[7]};
  }
}

// ---------------- head: thread per (node,rel) key; mean of z[src,rel] -> reduce -> softmax ----

__global__ void fused_head2(const float* __restrict__ zt,
                            const int* __restrict__ ssrc,
                            const int* __restrict__ offs,
                            float* __restrict__ out){
  int k = blockIdx.x * 256 + threadIdx.x;
  if (k >= NKEY) return;                  // whole waves exit; 4-groups stay intact
  int r = k & 3;
  int beg = iclamp(offs[k], 0, N_EDGES);
  int end = iclamp(offs[k + 1], beg, N_EDGES);
  float a0 = 0.f, a1 = 0.f, b0 = 0.f, b1 = 0.f, c0 = 0.f, c1 = 0.f, d0 = 0.f, d1 = 0.f;
  int i = beg;
  for (; i + 4 <= end; i += 4){
    int s0 = iclamp(ssrc[i],     0, N_NODES - 1);
    int s1 = iclamp(ssrc[i + 1], 0, N_NODES - 1);
    int s2 = iclamp(ssrc[i + 2], 0, N_NODES - 1);
    int s3 = iclamp(ssrc[i + 3], 0, N_NODES - 1);
    float2 v0 = *(const float2*)(zt + (size_t)s0 * 8 + r * 2);
    float2 v1 = *(const float2*)(zt + (size_t)s1 * 8 + r * 2);
    float2 v2 = *(const float2*)(zt + (size_t)s2 * 8 + r * 2);
    float2 v3 = *(const float2*)(zt + (size_t)s3 * 8 + r * 2);
    a0 += v0.x; a1 += v0.y;
    b0 += v1.x; b1 += v1.y;
    c0 += v2.x; c1 += v2.y;
    d0 += v3.x; d1 += v3.y;
  }
  for (; i < end; i++){
    int s = iclamp(ssrc[i], 0, N_NODES - 1);
    float2 v = *(const float2*)(zt + (size_t)s * 8 + r * 2);
    a0 += v.x; a1 += v.y;
  }
  int cnt = end - beg;
  float sc = (cnt > 0) ? 1.0f / (float)cnt : 0.0f;
  float dA = (a0 + b0 + c0 + d0) * sc;
  float dB = (a1 + b1 + c1 + d1) * sc;
  // sum the 4 relations (4 consecutive lanes of this wave)
  dA += __shfl_xor(dA, 1); dB += __shfl_xor(dB, 1);
  dA += __shfl_xor(dA, 2); dB += __shfl_xor(dB, 2);
  if (r == 0){
    int n = k >> 2;
    float mx = fmaxf(dA, dB);
    float e0 = __expf(dA - mx), e1 = __expf(dB - mx);
    float inv = 1.0f / (e0 + e1);
    *(float2*)(out + 2 * n) = (float2){e0 * inv, e1 * inv};            // softmax [N,2]
    *(float2*)(out + 2 * N_NODES + 2 * n) = (float2){dA, dB};          // logits  [N,2]
  }
}

// ---------------- launch ----------------

extern "C" void kernel_launch(void* const* d_in, const int* in_sizes, int n_in,
                              void* d_out, int out_size, void* d_ws, size_t ws_size,
                              hipStream_t stream){
  const float* x  = (const float*)d_in[0];
  const int* ei   = (const int*)d_in[1];
  const int* et   = (const int*)d_in[2];
  const float* W1 = (const float*)d_in[3];
  const float* W2 = (const float*)d_in[4];
  const float* W3 = (const float*)d_in[5];
  float* out = (float*)d_out;
  const int* src = ei;
  const int* dst = ei + N_EDGES;

  // workspace layout: ~61 MB total
  char* p = (char*)d_ws;
  auto alloc = [&](size_t bytes) -> char* {
    char* q = p; p += (bytes + 63) & ~(size_t)63; return q;
  };
  int* counts = (int*)alloc((size_t)NKEY * 4);          // reused as cursor
  int* cursor = counts;
  int* offs   = (int*)alloc((size_t)(NKEY + 1) * 4);
  int* bsums  = (int*)alloc(1024 * 4);
  int* ssrc   = (int*)alloc((size_t)N_EDGES * 4);
  unsigned short* Bt = (unsigned short*)alloc((size_t)DDIM * KDIM * 2);
  unsigned short* h1 = (unsigned short*)alloc((size_t)N_NODES * DDIM * 2);
  unsigned short* h2 = (unsigned short*)alloc((size_t)N_NODES * DDIM * 2);
  unsigned* xb = (unsigned*)h2;   // x-as-bf16 lives in h2's slot (dead until layer-2 output)
  float* zt = (float*)h1;         // z table aliases h1 (dead after layer-2 reads it)

  // sort edges by (dst, relation)
  hipMemsetAsync(counts, 0, (size_t)NKEY * 4, stream);
  hist_kernel<<<N_EDGES / 256, 256, 0, stream>>>(dst, et, counts);
  int nb = (NKEY + 1023) / 1024;  // 391
  scan_local<<<nb, 1024, 0, stream>>>(counts, offs, bsums, NKEY);
  scan_sums<<<1, 1024, 0, stream>>>(bsums, nb);
  scan_add<<<nb, 1024, 0, stream>>>(offs, cursor, bsums, NKEY, N_EDGES);
  scatter_kernel<<<N_EDGES / 256, 256, 0, stream>>>(src, dst, et, cursor, ssrc);

  int fgrid = (N_NODES + 63) / 64;  // 1563

  // layer 1: x -> packed bf16, agg -> @W1 -> tanh -> h1
  convert_x<<<(N_NODES * 64) / 256, 256, 0, stream>>>(x, xb);
  transpose_w<<<(DDIM * KDIM) / 256, 256, 0, stream>>>(W1, Bt);
  fused_layer<<<fgrid, 256, 0, stream>>>(xb, ssrc, offs, (const __bf16*)Bt, h1);
  // layer 2: h1 -> h2 (xb dead from here on)
  transpose_w<<<(DDIM * KDIM) / 256, 256, 0, stream>>>(W2, Bt);
  fused_layer<<<fgrid, 256, 0, stream>>>((const unsigned*)h1, ssrc, offs, (const __bf16*)Bt, h2);
  // layer 3 head: z = h2 @ W3 per relation (8 f32/node), then 8 B/edge gather + softmax
  compute_z<<<N_NODES / 4, 256, 0, stream>>>((const unsigned*)h2, W3, zt);
  fused_head2<<<(NKEY + 255) / 256, 256, 0, stream>>>(zt, ssrc, offs, out);
}